// Round 10
// baseline (279.514 us; speedup 1.0000x reference)
//
#include <hip/hip_runtime.h>
#include <math.h>

#define B   64
#define M   1024
#define RNN 1024
#define H   512
#define D   2048

#define NCHUNK 16
#define CROWS  (M / NCHUNK)   // 64 rows per block
#define RPW    (CROWS / 4)    // 16 rows per wave

// tanh(x) = sign(x) * (1 - e^{-2|x|}) / (1 + e^{-2|x|}); rcp via v_rcp_f32 (~1 ulp)
__device__ __forceinline__ float fast_tanh(float x) {
    float ax = fabsf(x);
    float t  = __expf(-2.0f * ax);
    float r  = (1.0f - t) * __builtin_amdgcn_rcpf(1.0f + t);
    return copysignf(r, x);
}

// Tiled wah = h @ W^T. grid (H/8, B/16), 256 threads.
__global__ __launch_bounds__(256) void k_wah(const float* __restrict__ h,
                                             const float* __restrict__ W,
                                             float* __restrict__ wah) {
    const int tid = threadIdx.x, lane = tid & 63, w = tid >> 6;
    const int bt = blockIdx.y * 16;
    const int j0 = blockIdx.x * 8 + w * 2;

    __shared__ float s_h[16 * RNN];        // 64KB
    const float4* h4  = (const float4*)(h + (size_t)bt * RNN);
    float4*       sh4 = (float4*)s_h;
#pragma unroll
    for (int k = 0; k < 16; ++k)
        sh4[tid + k * 256] = h4[tid + k * 256];

    const float4* Wa = (const float4*)(W + (size_t)j0 * RNN);
    const float4* Wb = (const float4*)(W + (size_t)(j0 + 1) * RNN);
    float4 wa[4], wb[4];
#pragma unroll
    for (int k = 0; k < 4; ++k) { wa[k] = Wa[lane + 64 * k]; wb[k] = Wb[lane + 64 * k]; }
    __syncthreads();

    for (int b = 0; b < 16; ++b) {
        float d0 = 0.0f, d1 = 0.0f;
#pragma unroll
        for (int k = 0; k < 4; ++k) {
            float4 hv = sh4[b * 256 + lane + 64 * k];
            d0 += hv.x * wa[k].x + hv.y * wa[k].y + hv.z * wa[k].z + hv.w * wa[k].w;
            d1 += hv.x * wb[k].x + hv.y * wb[k].y + hv.z * wb[k].z + hv.w * wb[k].w;
        }
#pragma unroll
        for (int off = 32; off > 0; off >>= 1) {
            d0 += __shfl_xor(d0, off);
            d1 += __shfl_xor(d1, off);
        }
        if (lane == 0)
            *(float2*)(wah + (size_t)(bt + b) * H + j0) = make_float2(d0, d1);
    }
}

// Fused kernel, r8 structure (wave-independent, no mid-block barriers) with the
// vmcnt-drain fix: all 16 mask words prefetched to registers up front, so no
// branch ever waits on a just-issued load (which would s_waitcnt vmcnt(0) and
// drain the feats stream). Per-wave phase split: phase 1 computes e[0..15] in
// registers from p_att (rows independent, loads pipeline); phase 2 is a pure
// feats stream -- branch-on-register, no cross-lane ops, 2 rows of loads in
// flight. Waves desynchronize so the two HBM streams mix chip-wide.
__global__ __launch_bounds__(256, 4) void k_fused(const float* __restrict__ wah,
                                                  const float* __restrict__ p_att,
                                                  const int* __restrict__ mask,
                                                  const float* __restrict__ w_alpha,
                                                  const float* __restrict__ feats,
                                                  float* __restrict__ partial,
                                                  float* __restrict__ zpart) {
    const int b   = blockIdx.x;
    const int c   = blockIdx.y;
    const int tid = threadIdx.x;
    const int lane = tid & 63;
    const int w    = tid >> 6;

    __shared__ float s_acc[4][D];    // 32KB

    const float4* wh4 = (const float4*)(wah + (size_t)b * H);
    const float4* wa4 = (const float4*)w_alpha;
    float4 wh0 = wh4[lane], wh1 = wh4[lane + 64];
    float4 wa0 = wa4[lane], wa1 = wa4[lane + 64];

    const int m0 = c * CROWS + w * RPW;      // this wave's 16 rows

    // ---- mask prefetch: 16 ints in registers, loaded before any branching
    const int* mrow = mask + (size_t)b * M + m0;
    int mk[RPW];
    *(int4*)&mk[0]  = *(const int4*)(mrow);
    *(int4*)&mk[4]  = *(const int4*)(mrow + 4);
    *(int4*)&mk[8]  = *(const int4*)(mrow + 8);
    *(int4*)&mk[12] = *(const int4*)(mrow + 12);

    // ---- phase 1: e[r] = exp(logit) for this wave's rows (registers only)
    const float4* pb4 = (const float4*)(p_att + ((size_t)b * M + m0) * H);
    float e[RPW];
    float zsum = 0.0f;
#pragma unroll
    for (int r = 0; r < RPW; ++r) {
        e[r] = 0.0f;
        if (mk[r] != 0) {                     // register test, wave-uniform
            float4 p0 = pb4[(size_t)r * (H / 4) + lane];
            float4 p1 = pb4[(size_t)r * (H / 4) + 64 + lane];
            float s = fast_tanh(p0.x + wh0.x) * wa0.x
                    + fast_tanh(p0.y + wh0.y) * wa0.y
                    + fast_tanh(p0.z + wh0.z) * wa0.z
                    + fast_tanh(p0.w + wh0.w) * wa0.w
                    + fast_tanh(p1.x + wh1.x) * wa1.x
                    + fast_tanh(p1.y + wh1.y) * wa1.y
                    + fast_tanh(p1.z + wh1.z) * wa1.z
                    + fast_tanh(p1.w + wh1.w) * wa1.w;
#pragma unroll
            for (int off = 32; off > 0; off >>= 1)
                s += __shfl_xor(s, off);
            e[r] = __expf(s);                 // uniform across lanes
            zsum += e[r];
        }
    }
    if (lane == 0) zpart[(size_t)(c * 4 + w) * B + b] = zsum;

    // ---- phase 2: pure feats stream, full-D accumulator per wave
    float4 acc[8];
#pragma unroll
    for (int j = 0; j < 8; ++j) acc[j] = make_float4(0.f, 0.f, 0.f, 0.f);

    const float4* fb4 = (const float4*)(feats + ((size_t)b * M + m0) * D);
#pragma unroll
    for (int r = 0; r < RPW; ++r) {
        if (e[r] != 0.0f) {                   // register test, no vmcnt wait
            const float4* fr = fb4 + (size_t)r * (D / 4) + lane;
            float ev = e[r];
            float4 f0 = fr[0],   f1 = fr[64],  f2 = fr[128], f3 = fr[192];
            float4 f4 = fr[256], f5 = fr[320], f6 = fr[384], f7 = fr[448];
            acc[0].x += ev * f0.x; acc[0].y += ev * f0.y; acc[0].z += ev * f0.z; acc[0].w += ev * f0.w;
            acc[1].x += ev * f1.x; acc[1].y += ev * f1.y; acc[1].z += ev * f1.z; acc[1].w += ev * f1.w;
            acc[2].x += ev * f2.x; acc[2].y += ev * f2.y; acc[2].z += ev * f2.z; acc[2].w += ev * f2.w;
            acc[3].x += ev * f3.x; acc[3].y += ev * f3.y; acc[3].z += ev * f3.z; acc[3].w += ev * f3.w;
            acc[4].x += ev * f4.x; acc[4].y += ev * f4.y; acc[4].z += ev * f4.z; acc[4].w += ev * f4.w;
            acc[5].x += ev * f5.x; acc[5].y += ev * f5.y; acc[5].z += ev * f5.z; acc[5].w += ev * f5.w;
            acc[6].x += ev * f6.x; acc[6].y += ev * f6.y; acc[6].z += ev * f6.z; acc[6].w += ev * f6.w;
            acc[7].x += ev * f7.x; acc[7].y += ev * f7.y; acc[7].z += ev * f7.z; acc[7].w += ev * f7.w;
        }
    }

    // ---- cross-wave reduce via LDS (single end-of-kernel barrier)
#pragma unroll
    for (int j = 0; j < 8; ++j)
        *(float4*)&s_acc[w][j * 256 + lane * 4] = acc[j];
    __syncthreads();

    float* pout = partial + ((size_t)c * B + b) * D;
#pragma unroll
    for (int k = 0; k < 8; ++k) {
        int d = k * 256 + tid;
        pout[d] = (s_acc[0][d] + s_acc[1][d]) + (s_acc[2][d] + s_acc[3][d]);
    }
}

// out[b,d] = (sum_c partial[c][b][d]) / (sum_cw zpart[cw][b])
__global__ __launch_bounds__(256) void k_reduce(const float* __restrict__ partial,
                                                const float* __restrict__ zpart,
                                                float* __restrict__ out) {
    int i4 = blockIdx.x * 256 + threadIdx.x;   // float4 index over B*D/4
    int b  = i4 >> 9;                          // uniform per block
    float Z = 0.0f;
#pragma unroll
    for (int cw = 0; cw < NCHUNK * 4; ++cw)
        Z += zpart[(size_t)cw * B + b];
    const float4* p4 = (const float4*)partial;
    float4 s = p4[i4];
#pragma unroll
    for (int c = 1; c < NCHUNK; ++c) {
        float4 v = p4[(size_t)c * (B * D / 4) + i4];
        s.x += v.x; s.y += v.y; s.z += v.z; s.w += v.w;
    }
    float inv = 1.0f / Z;
    float4 r = {s.x * inv, s.y * inv, s.z * inv, s.w * inv};
    ((float4*)out)[i4] = r;
}

extern "C" void kernel_launch(void* const* d_in, const int* in_sizes, int n_in,
                              void* d_out, int out_size, void* d_ws, size_t ws_size,
                              hipStream_t stream) {
    const float* h       = (const float*)d_in[0];
    const float* feats   = (const float*)d_in[1];
    const int*   mask    = (const int*)d_in[2];
    const float* p_att   = (const float*)d_in[3];
    const float* W_ah    = (const float*)d_in[4];
    const float* w_alpha = (const float*)d_in[5];
    float* out = (float*)d_out;

    float* ws      = (float*)d_ws;
    float* wah     = ws;                       // B*H floats
    float* zpart   = wah + B * H;              // NCHUNK*4*B floats
    float* partial = zpart + NCHUNK * 4 * B;   // NCHUNK*B*D floats (8MB)

    k_wah   <<<dim3(H / 8, B / 16), 256, 0, stream>>>(h, W_ah, wah);
    k_fused <<<dim3(B, NCHUNK), 256, 0, stream>>>(wah, p_att, mask, w_alpha, feats,
                                                  partial, zpart);
    k_reduce<<<dim3(B * D / 1024), 256, 0, stream>>>(partial, zpart, out);
}

// Round 11
// 76.886 us; speedup vs baseline: 3.6354x; 3.6354x over previous
//
#include <hip/hip_runtime.h>
#include <math.h>

#define B   64
#define M   1024
#define RNN 1024
#define H   512
#define D   2048

#define NCHUNK 16
#define CROWS  (M / NCHUNK)   // 64 rows per block
#define RPW    (CROWS / 4)    // 16 rows per wave

// tanh(x) = sign(x) * (1 - e^{-2|x|}) / (1 + e^{-2|x|}); rcp via v_rcp_f32 (~1 ulp)
__device__ __forceinline__ float fast_tanh(float x) {
    float ax = fabsf(x);
    float t  = __expf(-2.0f * ax);
    float r  = (1.0f - t) * __builtin_amdgcn_rcpf(1.0f + t);
    return copysignf(r, x);
}

// Tiled wah = h @ W^T. grid (H/8, B/16), 256 threads.
__global__ __launch_bounds__(256) void k_wah(const float* __restrict__ h,
                                             const float* __restrict__ W,
                                             float* __restrict__ wah) {
    const int tid = threadIdx.x, lane = tid & 63, w = tid >> 6;
    const int bt = blockIdx.y * 16;
    const int j0 = blockIdx.x * 8 + w * 2;

    __shared__ float s_h[16 * RNN];        // 64KB
    const float4* h4  = (const float4*)(h + (size_t)bt * RNN);
    float4*       sh4 = (float4*)s_h;
#pragma unroll
    for (int k = 0; k < 16; ++k)
        sh4[tid + k * 256] = h4[tid + k * 256];

    const float4* Wa = (const float4*)(W + (size_t)j0 * RNN);
    const float4* Wb = (const float4*)(W + (size_t)(j0 + 1) * RNN);
    float4 wa[4], wb[4];
#pragma unroll
    for (int k = 0; k < 4; ++k) { wa[k] = Wa[lane + 64 * k]; wb[k] = Wb[lane + 64 * k]; }
    __syncthreads();

    for (int b = 0; b < 16; ++b) {
        float d0 = 0.0f, d1 = 0.0f;
#pragma unroll
        for (int k = 0; k < 4; ++k) {
            float4 hv = sh4[b * 256 + lane + 64 * k];
            d0 += hv.x * wa[k].x + hv.y * wa[k].y + hv.z * wa[k].z + hv.w * wa[k].w;
            d1 += hv.x * wb[k].x + hv.y * wb[k].y + hv.z * wb[k].z + hv.w * wb[k].w;
        }
#pragma unroll
        for (int off = 32; off > 0; off >>= 1) {
            d0 += __shfl_xor(d0, off);
            d1 += __shfl_xor(d1, off);
        }
        if (lane == 0)
            *(float2*)(wah + (size_t)(bt + b) * H + j0) = make_float2(d0, d1);
    }
}

// r8 structure restored (per-row interleave, rolled loop, immediate e use,
// small live state -- no spills). Single change: the 16 per-row mask loads are
// replaced by ONE lane-parallel load + __ballot packed into a uniform register;
// the row branch tests a register bit, so no memory wait can gate the stream.
__global__ __launch_bounds__(256, 4) void k_fused(const float* __restrict__ wah,
                                                  const float* __restrict__ p_att,
                                                  const int* __restrict__ mask,
                                                  const float* __restrict__ w_alpha,
                                                  const float* __restrict__ feats,
                                                  float* __restrict__ partial,
                                                  float* __restrict__ zpart) {
    const int b   = blockIdx.x;
    const int c   = blockIdx.y;
    const int tid = threadIdx.x;
    const int lane = tid & 63;
    const int w    = tid >> 6;

    __shared__ float s_acc[4][D];    // 32KB

    const float4* wh4 = (const float4*)(wah + (size_t)b * H);
    const float4* wa4 = (const float4*)w_alpha;
    float4 wh0 = wh4[lane], wh1 = wh4[lane + 64];
    float4 wa0 = wa4[lane], wa1 = wa4[lane + 64];

    const int m0 = c * CROWS + w * RPW;      // this wave's 16 rows

    // one mask load per lane (lanes repeat every 16), ballot -> uniform bits
    const int* mrow = mask + (size_t)b * M + m0;
    int mv = mrow[lane & (RPW - 1)];
    unsigned long long bal = __ballot(mv != 0);
    const unsigned mbits = (unsigned)(bal & 0xFFFFu);   // bit r = row r unmasked

    const float4* pb4 = (const float4*)(p_att + ((size_t)b * M + m0) * H);
    const float4* fb4 = (const float4*)(feats + ((size_t)b * M + m0) * D);

    float4 acc[8];
#pragma unroll
    for (int j = 0; j < 8; ++j) acc[j] = make_float4(0.f, 0.f, 0.f, 0.f);
    float zsum = 0.0f;

    for (int r = 0; r < RPW; ++r) {
        if ((mbits >> r) & 1u) {              // uniform register test
            const float4* pr = pb4 + (size_t)r * (H / 4);
            const float4* fr = fb4 + (size_t)r * (D / 4) + lane;
            float4 p0 = pr[lane], p1 = pr[lane + 64];
            float4 f0 = fr[0],   f1 = fr[64],  f2 = fr[128], f3 = fr[192];
            float4 f4 = fr[256], f5 = fr[320], f6 = fr[384], f7 = fr[448];

            float s = fast_tanh(p0.x + wh0.x) * wa0.x
                    + fast_tanh(p0.y + wh0.y) * wa0.y
                    + fast_tanh(p0.z + wh0.z) * wa0.z
                    + fast_tanh(p0.w + wh0.w) * wa0.w
                    + fast_tanh(p1.x + wh1.x) * wa1.x
                    + fast_tanh(p1.y + wh1.y) * wa1.y
                    + fast_tanh(p1.z + wh1.z) * wa1.z
                    + fast_tanh(p1.w + wh1.w) * wa1.w;
#pragma unroll
            for (int off = 32; off > 0; off >>= 1)
                s += __shfl_xor(s, off);
            float e = __expf(s);              // uniform across lanes
            zsum += e;

            acc[0].x += e * f0.x; acc[0].y += e * f0.y; acc[0].z += e * f0.z; acc[0].w += e * f0.w;
            acc[1].x += e * f1.x; acc[1].y += e * f1.y; acc[1].z += e * f1.z; acc[1].w += e * f1.w;
            acc[2].x += e * f2.x; acc[2].y += e * f2.y; acc[2].z += e * f2.z; acc[2].w += e * f2.w;
            acc[3].x += e * f3.x; acc[3].y += e * f3.y; acc[3].z += e * f3.z; acc[3].w += e * f3.w;
            acc[4].x += e * f4.x; acc[4].y += e * f4.y; acc[4].z += e * f4.z; acc[4].w += e * f4.w;
            acc[5].x += e * f5.x; acc[5].y += e * f5.y; acc[5].z += e * f5.z; acc[5].w += e * f5.w;
            acc[6].x += e * f6.x; acc[6].y += e * f6.y; acc[6].z += e * f6.z; acc[6].w += e * f6.w;
            acc[7].x += e * f7.x; acc[7].y += e * f7.y; acc[7].z += e * f7.z; acc[7].w += e * f7.w;
        }
    }

    if (lane == 0) zpart[(size_t)(c * 4 + w) * B + b] = zsum;

    // cross-wave reduce via LDS (single barrier)
#pragma unroll
    for (int j = 0; j < 8; ++j)
        *(float4*)&s_acc[w][j * 256 + lane * 4] = acc[j];
    __syncthreads();

    float* pout = partial + ((size_t)c * B + b) * D;
#pragma unroll
    for (int k = 0; k < 8; ++k) {
        int d = k * 256 + tid;
        pout[d] = (s_acc[0][d] + s_acc[1][d]) + (s_acc[2][d] + s_acc[3][d]);
    }
}

// out[b,d] = (sum_c partial[c][b][d]) / (sum_cw zpart[cw][b])
__global__ __launch_bounds__(256) void k_reduce(const float* __restrict__ partial,
                                                const float* __restrict__ zpart,
                                                float* __restrict__ out) {
    int i4 = blockIdx.x * 256 + threadIdx.x;   // float4 index over B*D/4
    int b  = i4 >> 9;                          // uniform per block
    float Z = 0.0f;
#pragma unroll
    for (int cw = 0; cw < NCHUNK * 4; ++cw)
        Z += zpart[(size_t)cw * B + b];
    const float4* p4 = (const float4*)partial;
    float4 s = p4[i4];
#pragma unroll
    for (int c = 1; c < NCHUNK; ++c) {
        float4 v = p4[(size_t)c * (B * D / 4) + i4];
        s.x += v.x; s.y += v.y; s.z += v.z; s.w += v.w;
    }
    float inv = 1.0f / Z;
    float4 r = {s.x * inv, s.y * inv, s.z * inv, s.w * inv};
    ((float4*)out)[i4] = r;
}

extern "C" void kernel_launch(void* const* d_in, const int* in_sizes, int n_in,
                              void* d_out, int out_size, void* d_ws, size_t ws_size,
                              hipStream_t stream) {
    const float* h       = (const float*)d_in[0];
    const float* feats   = (const float*)d_in[1];
    const int*   mask    = (const int*)d_in[2];
    const float* p_att   = (const float*)d_in[3];
    const float* W_ah    = (const float*)d_in[4];
    const float* w_alpha = (const float*)d_in[5];
    float* out = (float*)d_out;

    float* ws      = (float*)d_ws;
    float* wah     = ws;                       // B*H floats
    float* zpart   = wah + B * H;              // NCHUNK*4*B floats
    float* partial = zpart + NCHUNK * 4 * B;   // NCHUNK*B*D floats (8MB)

    k_wah   <<<dim3(H / 8, B / 16), 256, 0, stream>>>(h, W_ah, wah);
    k_fused <<<dim3(B, NCHUNK), 256, 0, stream>>>(wah, p_att, mask, w_alpha, feats,
                                                  partial, zpart);
    k_reduce<<<dim3(B * D / 1024), 256, 0, stream>>>(partial, zpart, out);
}